// Round 4
// baseline (483.170 us; speedup 1.0000x reference)
//
#include <hip/hip_runtime.h>
#include <hip/hip_bf16.h>

// GAT layer, N=8192, F=128.
//   k0: u = W@a1, v = W@a2                     (fp32, trivial)
//   k1: Wh = h@W -> WhT (bf16 [F][N]); e_src = h@u, e_dst = h@v (fp32)
//   k2: fused masked-softmax(P) @ Wh. NO LDS, NO barriers: each lane
//       generates its own MFMA A-fragment (P values) in registers.
//       Wave = 16 rows x 128 cols, j-seg 1024. Partials -> ws.
//   k3: out[i][:] = (sum_seg num) / (sum_seg den)
//
// ws: [0,2MB) WhT | u,v,e_src,e_dst | num_ws 8x4MB @4MB | den_ws 8x32KB @36MB

#define NN 8192
#define FF 128
#define SEGS 8
#define JSEG (NN / SEGS)     // 1024
#define NK (JSEG / 32)       // 32 k-steps per wave

typedef __bf16 bf16x8 __attribute__((ext_vector_type(8)));
typedef float floatx4 __attribute__((ext_vector_type(4)));

__device__ __forceinline__ unsigned short f2b(float f) {
    unsigned int u = __float_as_uint(f);
    return (unsigned short)((u + 0x7FFFu + ((u >> 16) & 1u)) >> 16);
}
__device__ __forceinline__ unsigned int pk2(float a, float b) {
    return (unsigned int)f2b(a) | ((unsigned int)f2b(b) << 16);
}

// ---------------- k0 ----------------
__global__ __launch_bounds__(128) void k0_uv(const float* __restrict__ W,
                                             const float* __restrict__ a,
                                             float* __restrict__ u,
                                             float* __restrict__ v) {
    int k = blockIdx.x, t = threadIdx.x;
    float wv = W[k * FF + t];
    float p1 = wv * a[t];
    float p2 = wv * a[FF + t];
    for (int off = 32; off; off >>= 1) {
        p1 += __shfl_down(p1, off);
        p2 += __shfl_down(p2, off);
    }
    __shared__ float r[4];
    if ((t & 63) == 0) { r[(t >> 6) * 2] = p1; r[(t >> 6) * 2 + 1] = p2; }
    __syncthreads();
    if (t == 0) { u[k] = r[0] + r[2]; v[k] = r[1] + r[3]; }
}

// ---------------- k1 ----------------
__global__ __launch_bounds__(256) void k1_wh(const float* __restrict__ h,
                                             const float* __restrict__ W,
                                             const float* __restrict__ u,
                                             const float* __restrict__ v,
                                             unsigned short* __restrict__ WhT,
                                             float* __restrict__ e_src,
                                             float* __restrict__ e_dst) {
    __shared__ float hL[32 * 132];
    __shared__ float wL[128 * 132];
    __shared__ float uL[128], vL[128];
    __shared__ unsigned short tL[128 * 40];

    int t = threadIdx.x;
    int i0 = blockIdx.x * 32;

    {
        int row = t >> 3, c = (t & 7) * 16;
        const float4* s = (const float4*)&h[(i0 + row) * FF + c];
        float4* d = (float4*)&hL[row * 132 + c];
        #pragma unroll
        for (int j = 0; j < 4; j++) d[j] = s[j];
    }
    {
        int row = t >> 1, c = (t & 1) * 64;
        const float4* s = (const float4*)&W[row * FF + c];
        float4* d = (float4*)&wL[row * 132 + c];
        #pragma unroll
        for (int j = 0; j < 16; j++) d[j] = s[j];
    }
    if (t < 128) { uL[t] = u[t]; vL[t] = v[t]; }
    __syncthreads();

    int r0 = (t & 7) * 4;
    int c0 = (t >> 3) * 4;
    float acc[4][4] = {};
    for (int k0 = 0; k0 < 128; k0 += 4) {
        float4 hr[4], wr[4];
        #pragma unroll
        for (int i = 0; i < 4; i++) hr[i] = *(const float4*)&hL[(r0 + i) * 132 + k0];
        #pragma unroll
        for (int i = 0; i < 4; i++) wr[i] = *(const float4*)&wL[(k0 + i) * 132 + c0];
        #pragma unroll
        for (int kj = 0; kj < 4; kj++) {
            #pragma unroll
            for (int ri = 0; ri < 4; ri++) {
                float hvv = ((const float*)&hr[ri])[kj];
                const float* wvv = (const float*)&wr[kj];
                #pragma unroll
                for (int cj = 0; cj < 4; cj++) acc[ri][cj] = fmaf(hvv, wvv[cj], acc[ri][cj]);
            }
        }
    }
    #pragma unroll
    for (int ri = 0; ri < 4; ri++)
        #pragma unroll
        for (int cj = 0; cj < 4; cj++)
            tL[(c0 + cj) * 40 + r0 + ri] = f2b(acc[ri][cj]);
    __syncthreads();

    if (t < 64) {
        int row = t & 31;
        const float* sv = (t < 32) ? uL : vL;
        float s = 0.f;
        for (int k = 0; k < 128; k += 4) {
            float4 h4 = *(const float4*)&hL[row * 132 + k];
            float4 s4 = *(const float4*)&sv[k];
            s = fmaf(h4.x, s4.x, s); s = fmaf(h4.y, s4.y, s);
            s = fmaf(h4.z, s4.z, s); s = fmaf(h4.w, s4.w, s);
        }
        (t < 32 ? e_src : e_dst)[i0 + row] = s;
    }
    {
        int f = t & 127, half = t >> 7;
        const uint4* s = (const uint4*)&tL[f * 40 + half * 16];
        uint4* d = (uint4*)&WhT[f * NN + i0 + half * 16];
        d[0] = s[0]; d[1] = s[1];
    }
}

// ---------------- k2: barrier-free, register A-fragments ----------------
__device__ __forceinline__ float mask_w(int a, float x) {
    float l = fmaxf(x, 0.2f * x);
    return a > 0 ? __expf(l) : 0.f;
}

__global__ __launch_bounds__(512, 4) void k2_gat(const int* __restrict__ adj,
                                                 const unsigned short* __restrict__ WhT,
                                                 const float* __restrict__ e_src,
                                                 const float* __restrict__ e_dst,
                                                 float* __restrict__ num_ws,
                                                 float* __restrict__ den_ws) {
    int t = threadIdx.x;
    int bx = blockIdx.x;
    int it = bx >> 3, seg = bx & 7;
    int i0 = it * 128;
    int jb = seg * JSEG;

    int lane = t & 63, wave = t >> 6;
    int mrow = lane & 15, quad = lane >> 4;
    int irow = i0 + wave * 16 + mrow;        // the P row this lane generates

    float es = e_src[irow];
    const int*   Ap = adj + (size_t)irow * NN + jb + quad * 8;
    const float* Ep = e_dst + jb + quad * 8;

    // B base pointers: col group bn, B[n=mrow][k] contiguous per lane
    const unsigned short* Bp[8];
    #pragma unroll
    for (int bn = 0; bn < 8; bn++)
        Bp[bn] = WhT + (size_t)(bn * 16 + mrow) * NN + jb + quad * 8;

    floatx4 acc[8] = {};
    float dsum = 0.f;

    // prefetch k-step 0
    int4   a0 = *(const int4*)Ap;
    int4   a1 = *(const int4*)(Ap + 4);
    float4 e0 = *(const float4*)Ep;
    float4 e1 = *(const float4*)(Ep + 4);

    for (int ks = 0; ks < NK; ks++) {
        // B fragments for this k-step (L1/L2-resident WhT)
        bf16x8 B[8];
        #pragma unroll
        for (int bn = 0; bn < 8; bn++)
            B[bn] = *(const bf16x8*)(Bp[bn] + ks * 32);

        // prefetch next k-step's adj / e_dst (clamped to avoid OOB tail)
        int nxt = (ks + 1 < NK ? ks + 1 : ks) * 32;
        int4   na0 = *(const int4*)(Ap + nxt);
        int4   na1 = *(const int4*)(Ap + nxt + 4);
        float4 ne0 = *(const float4*)(Ep + nxt);
        float4 ne1 = *(const float4*)(Ep + nxt + 4);

        // generate this lane's 8 P values (A-frag: k = quad*8 + j)
        float w0 = mask_w(a0.x, es + e0.x);
        float w1 = mask_w(a0.y, es + e0.y);
        float w2 = mask_w(a0.z, es + e0.z);
        float w3 = mask_w(a0.w, es + e0.w);
        float w4 = mask_w(a1.x, es + e1.x);
        float w5 = mask_w(a1.y, es + e1.y);
        float w6 = mask_w(a1.z, es + e1.z);
        float w7 = mask_w(a1.w, es + e1.w);
        dsum += ((w0 + w1) + (w2 + w3)) + ((w4 + w5) + (w6 + w7));

        union { unsigned int u[4]; bf16x8 v; } af;
        af.u[0] = pk2(w0, w1);
        af.u[1] = pk2(w2, w3);
        af.u[2] = pk2(w4, w5);
        af.u[3] = pk2(w6, w7);
        bf16x8 A = af.v;

        #pragma unroll
        for (int bn = 0; bn < 8; bn++)
            acc[bn] = __builtin_amdgcn_mfma_f32_16x16x32_bf16(A, B[bn], acc[bn], 0, 0, 0);

        a0 = na0; a1 = na1; e0 = ne0; e1 = ne1;
    }

    // denominator: this lane holds row irow's partial over its quad-slice
    dsum += __shfl_xor(dsum, 16);
    dsum += __shfl_xor(dsum, 32);
    if (quad == 0) den_ws[seg * NN + irow] = dsum;

    // numerator partials (C/D: col = lane&15, row = quad*4 + r)
    float* np = num_ws + (size_t)seg * NN * FF;
    #pragma unroll
    for (int bn = 0; bn < 8; bn++)
        #pragma unroll
        for (int r = 0; r < 4; r++) {
            int row = i0 + wave * 16 + quad * 4 + r;
            np[(size_t)row * FF + bn * 16 + mrow] = acc[bn][r];
        }
}

// ---------------- k3: merge seg partials, divide ----------------
__global__ __launch_bounds__(256) void k3_merge(const float* __restrict__ num_ws,
                                                const float* __restrict__ den_ws,
                                                float* __restrict__ out) {
    int idx = blockIdx.x * 256 + threadIdx.x;
    int i = idx >> 5;
    int c = (idx & 31) << 2;
    float4 s = make_float4(0.f, 0.f, 0.f, 0.f);
    float d = 0.f;
    #pragma unroll
    for (int sg = 0; sg < SEGS; sg++) {
        float4 vv = *(const float4*)&num_ws[(size_t)sg * NN * FF + (size_t)i * FF + c];
        s.x += vv.x; s.y += vv.y; s.z += vv.z; s.w += vv.w;
        d += den_ws[sg * NN + i];
    }
    float r = 1.0f / d;
    s.x *= r; s.y *= r; s.z *= r; s.w *= r;
    *(float4*)&out[(size_t)i * FF + c] = s;
}

extern "C" void kernel_launch(void* const* d_in, const int* in_sizes, int n_in,
                              void* d_out, int out_size, void* d_ws, size_t ws_size,
                              hipStream_t stream) {
    const float* h   = (const float*)d_in[0];
    const int*   adj = (const int*)d_in[1];
    const float* W   = (const float*)d_in[2];
    const float* a   = (const float*)d_in[3];
    float* out = (float*)d_out;

    char* ws = (char*)d_ws;
    unsigned short* WhT = (unsigned short*)ws;               // 2 MB
    float* u     = (float*)(ws + 2097152);
    float* v     = u + 128;
    float* e_src = (float*)(ws + 2097152 + 1024);
    float* e_dst = e_src + NN;
    float* num_ws = (float*)(ws + 4194304);                  // 32 MB
    float* den_ws = (float*)(ws + 4194304 + 33554432);       // 256 KB

    k0_uv<<<dim3(128), dim3(128), 0, stream>>>(W, a, u, v);
    k1_wh<<<dim3(256), dim3(256), 0, stream>>>(h, W, u, v, WhT, e_src, e_dst);
    k2_gat<<<dim3((NN / 128) * SEGS), dim3(512), 0, stream>>>(adj, WhT, e_src, e_dst, num_ws, den_ws);
    k3_merge<<<dim3(NN * FF / 4 / 256), dim3(256), 0, stream>>>(num_ws, den_ws, out);
}